// Round 6
// baseline (536.669 us; speedup 1.0000x reference)
//
#include <hip/hip_runtime.h>

#define N_NODES 100000
#define N_PAD 100352          // 392 * 256
#define NBLK 392
#define IN_FEAT 128
#define OUT_FEAT 128
#define NUM_RELS 64
#define EDGES_PER_REL 16384
#define NUM_BASES 16
#define E_TOTAL (NUM_RELS * EDGES_PER_REL)

typedef __bf16 bf16x8 __attribute__((ext_vector_type(8)));
typedef float floatx4 __attribute__((ext_vector_type(4)));

// ---------------------------------------------------------------------------
// W composition -> bf16 k-packed layout Wp[r][kp][n][j], k = kp*8+j
// ---------------------------------------------------------------------------
__global__ __launch_bounds__(256) void compose_w_bf16_kernel(
    const float* __restrict__ weight, const float* __restrict__ w_comp,
    __bf16* __restrict__ Wp) {
  int idx = blockIdx.x * 256 + threadIdx.x;
  int r = idx >> 14;
  int off = idx & 16383;
  int j = off & 7, n = (off >> 3) & 127, kp = off >> 10;
  int k = kp * 8 + j;
  const float* wc = w_comp + r * NUM_BASES;
  float acc = 0.f;
#pragma unroll
  for (int b = 0; b < NUM_BASES; ++b)
    acc += wc[b] * weight[b * 16384 + k * 128 + n];
  Wp[idx] = (__bf16)acc;
}

// loop_weight -> bf16 k-packed layout Lp[kp][n][j]
__global__ __launch_bounds__(256) void pack_loop_w_kernel(
    const float* __restrict__ loop_w, __bf16* __restrict__ Lp) {
  int idx = blockIdx.x * 256 + threadIdx.x;    // 16384
  int j = idx & 7, n = (idx >> 3) & 127, kp = idx >> 10;
  Lp[idx] = (__bf16)loop_w[(kp * 8 + j) * 128 + n];
}

__global__ __launch_bounds__(256) void compose_w_f32_kernel(
    const float* __restrict__ weight, const float* __restrict__ w_comp,
    float* __restrict__ W) {
  int idx = blockIdx.x * 256 + threadIdx.x;
  int r = idx >> 14;
  int io = idx & 16383;
  const float* wc = w_comp + r * NUM_BASES;
  float acc = 0.f;
#pragma unroll
  for (int b = 0; b < NUM_BASES; ++b)
    acc += wc[b] * weight[b * 16384 + io];
  W[idx] = acc;
}

// ---------------------------------------------------------------------------
// out[n] = h_bias + feat[n] @ loop_weight   (MFMA bf16, 64 nodes / block)
// ---------------------------------------------------------------------------
__global__ __launch_bounds__(256) void init_out_mfma(
    const float* __restrict__ feat, const __bf16* __restrict__ Lp,
    const float* __restrict__ bias, float* __restrict__ out) {
  __shared__ __bf16 A_lds[64 * 136];
  int t = threadIdx.x;
  long base = (long)blockIdx.x * 64;
#pragma unroll
  for (int j = 0; j < 8; ++j) {
    int idx = t + j * 256;
    int e = idx >> 5, k4 = idx & 31;
    long n = base + e;
    float4 v = make_float4(0.f, 0.f, 0.f, 0.f);
    if (n < N_NODES) v = ((const float4*)feat)[n * 32 + k4];
    __bf16 tb[4] = {(__bf16)v.x, (__bf16)v.y, (__bf16)v.z, (__bf16)v.w};
    *(ushort4*)&A_lds[e * 136 + k4 * 4] = *(ushort4*)tb;
  }
  __syncthreads();

  int wave = t >> 6, lane = t & 63;
  int m16 = lane & 15, quad = lane >> 4;
  floatx4 acc[8];
#pragma unroll
  for (int nt = 0; nt < 8; ++nt) acc[nt] = (floatx4){0.f, 0.f, 0.f, 0.f};

  const __bf16* a_base = &A_lds[(wave * 16 + m16) * 136 + quad * 8];
#pragma unroll
  for (int ks = 0; ks < 4; ++ks) {
    bf16x8 a = *(const bf16x8*)(a_base + ks * 32);
    int kp = ks * 4 + quad;
#pragma unroll
    for (int nt = 0; nt < 8; ++nt) {
      bf16x8 b = *(const bf16x8*)(Lp + (kp * 128 + nt * 16 + m16) * 8);
      acc[nt] = __builtin_amdgcn_mfma_f32_16x16x32_bf16(a, b, acc[nt], 0, 0, 0);
    }
  }

  float bv[8];
#pragma unroll
  for (int nt = 0; nt < 8; ++nt) bv[nt] = bias[nt * 16 + m16];
#pragma unroll
  for (int r = 0; r < 4; ++r) {
    long n = base + wave * 16 + quad * 4 + r;
    if (n < N_NODES) {
#pragma unroll
      for (int nt = 0; nt < 8; ++nt)
        out[n * 128 + nt * 16 + m16] = acc[nt][r] + bv[nt];
    }
  }
}

// ---------------------------------------------------------------------------
// Per-chunk CSR build
// ---------------------------------------------------------------------------
__global__ __launch_bounds__(256) void zero_kernel(int* __restrict__ p) {
  p[blockIdx.x * 256 + threadIdx.x] = 0;
}

__global__ __launch_bounds__(256) void hist8_kernel(
    const int* __restrict__ dst, int* __restrict__ cnt8, int cshift) {
  int e = blockIdx.x * 256 + threadIdx.x;
  int c = e >> cshift;
  atomicAdd(&cnt8[c * N_PAD + dst[e]], 1);
}

__global__ __launch_bounds__(256) void scan1_kernel(
    const int* __restrict__ cnt, int* __restrict__ row,
    int* __restrict__ bsum) {
  __shared__ int s[256];
  int t = threadIdx.x;
  int idx = blockIdx.x * 256 + t;
  int v = cnt[idx];
  s[t] = v;
  __syncthreads();
  for (int o = 1; o < 256; o <<= 1) {
    int x = (t >= o) ? s[t - o] : 0;
    __syncthreads();
    s[t] += x;
    __syncthreads();
  }
  row[idx] = s[t] - v;
  if (t == 255) bsum[blockIdx.x] = s[t];
}

__global__ __launch_bounds__(512) void scan2_kernel(
    const int* __restrict__ bsum, int* __restrict__ boff) {
  __shared__ int s[512];
  int t = threadIdx.x;
  int v = (t < NBLK) ? bsum[blockIdx.x * NBLK + t] : 0;
  s[t] = v;
  __syncthreads();
  for (int o = 1; o < 512; o <<= 1) {
    int x = (t >= o) ? s[t - o] : 0;
    __syncthreads();
    s[t] += x;
    __syncthreads();
  }
  if (t < NBLK) boff[blockIdx.x * NBLK + t] = s[t] - v;
}

__global__ __launch_bounds__(256) void scan3_kernel(
    int* __restrict__ row, const int* __restrict__ boff,
    int* __restrict__ fill) {
  int idx = blockIdx.x * 256 + threadIdx.x;
  int v = row[idx] + boff[blockIdx.x];
  row[idx] = v;
  fill[idx] = v;
}

__global__ __launch_bounds__(256) void scatter_pos_kernel(
    const int* __restrict__ dst, int* __restrict__ fill8,
    int* __restrict__ pos, int cshift) {
  int e = blockIdx.x * 256 + threadIdx.x;
  int c = e >> cshift;
  pos[e] = atomicAdd(&fill8[c * N_PAD + dst[e]], 1);
}

// ---------------------------------------------------------------------------
// Phase A (MFMA): msg[pos[e]] = bf16((feat[src[e]] @ W[rel]) * norm[e])
// 128 edges/block, 4 waves, M=32/wave (two A-frags share each B-frag).
// Epilogue bounces D through LDS -> 256B-contiguous row stores.
// ---------------------------------------------------------------------------
__global__ __launch_bounds__(256) void edge_gemm_mfma(
    const float* __restrict__ feat, const __bf16* __restrict__ Wp,
    const float* __restrict__ norm, const int* __restrict__ src,
    const int* __restrict__ pos, unsigned short* __restrict__ msg, int e_lo) {
  __shared__ __bf16 A_lds[128 * 136];          // 34.8 KB
  __shared__ int s_pos[128];
  __shared__ float s_norm[128];
  int t = threadIdx.x;
  long base = (long)e_lo + (long)blockIdx.x * 128;
  int rel = (int)(base >> 14);                 // 16384 % 128 == 0
  const __bf16* Wr = Wp + (long)rel * (IN_FEAT * OUT_FEAT);

  int s_src_t;
  if (t < 128) {
    s_src_t = src[base + t];
    s_pos[t] = pos[base + t];
    s_norm[t] = norm[base + t];
  }
  __shared__ int s_src[128];
  if (t < 128) s_src[t] = s_src_t;
  __syncthreads();
#pragma unroll
  for (int j = 0; j < 16; ++j) {
    int idx = t + j * 256;                     // 4096 float4s
    int e = idx >> 5, k4 = idx & 31;
    float4 v = ((const float4*)feat)[(long)s_src[e] * 32 + k4];
    __bf16 tb[4] = {(__bf16)v.x, (__bf16)v.y, (__bf16)v.z, (__bf16)v.w};
    *(ushort4*)&A_lds[e * 136 + k4 * 4] = *(ushort4*)tb;
  }
  __syncthreads();

  int wave = t >> 6, lane = t & 63;
  int m16 = lane & 15, quad = lane >> 4;
  floatx4 acc0[8], acc1[8];
#pragma unroll
  for (int nt = 0; nt < 8; ++nt) {
    acc0[nt] = (floatx4){0.f, 0.f, 0.f, 0.f};
    acc1[nt] = (floatx4){0.f, 0.f, 0.f, 0.f};
  }

  const __bf16* a_base = &A_lds[(wave * 32 + m16) * 136 + quad * 8];
#pragma unroll
  for (int ks = 0; ks < 4; ++ks) {
    bf16x8 a0 = *(const bf16x8*)(a_base + ks * 32);
    bf16x8 a1 = *(const bf16x8*)(a_base + 16 * 136 + ks * 32);
    int kp = ks * 4 + quad;
#pragma unroll
    for (int nt = 0; nt < 8; ++nt) {
      bf16x8 b = *(const bf16x8*)(Wr + (kp * 128 + nt * 16 + m16) * 8);
      acc0[nt] = __builtin_amdgcn_mfma_f32_16x16x32_bf16(a0, b, acc0[nt], 0, 0, 0);
      acc1[nt] = __builtin_amdgcn_mfma_f32_16x16x32_bf16(a1, b, acc1[nt], 0, 0, 0);
    }
  }

  // D (col=lane&15, row=quad*4+r) -> norm-scaled bf16 into reused A_lds tile
  __syncthreads();
#pragma unroll
  for (int r = 0; r < 4; ++r) {
    int e0 = wave * 32 + quad * 4 + r;
    int e1 = e0 + 16;
    float nm0 = s_norm[e0], nm1 = s_norm[e1];
#pragma unroll
    for (int nt = 0; nt < 8; ++nt) {
      A_lds[e0 * 136 + nt * 16 + m16] = (__bf16)(acc0[nt][r] * nm0);
      A_lds[e1 * 136 + nt * 16 + m16] = (__bf16)(acc1[nt][r] * nm1);
    }
  }
  __syncthreads();
  // re-read 16B/lane; each msg row written as one 256B contiguous burst
#pragma unroll
  for (int it = 0; it < 8; ++it) {
    int idx = it * 256 + t;
    int row = idx >> 4, seg = idx & 15;
    uint4 v = *(const uint4*)&A_lds[row * 136 + seg * 8];
    *(uint4*)(msg + (long)s_pos[row] * 128 + seg * 8) = v;
  }
}

// ---------------------------------------------------------------------------
// Phase B: CSR gather, 2 msg rows / iter (uint2/lane = 512B per wave-iter)
// ---------------------------------------------------------------------------
__global__ __launch_bounds__(256) void gather_csr_kernel(
    const unsigned short* __restrict__ msg, const int* __restrict__ rowc,
    float* __restrict__ out, int do_relu) {
  int wave = threadIdx.x >> 6, lane = threadIdx.x & 63;
  int n = blockIdx.x * 4 + wave;
  if (n >= N_NODES) return;
  int beg = rowc[n], end = rowc[n + 1];
  if (!do_relu && beg == end) return;
  int half = lane >> 5;
  int c4 = lane & 31;
  float s0 = 0.f, s1 = 0.f, s2 = 0.f, s3 = 0.f;
  for (int j = beg + half; j < end; j += 2) {
    uint2 m = *(const uint2*)(msg + (long)j * 128 + c4 * 4);
    s0 += __uint_as_float(m.x << 16);
    s1 += __uint_as_float(m.x & 0xFFFF0000u);
    s2 += __uint_as_float(m.y << 16);
    s3 += __uint_as_float(m.y & 0xFFFF0000u);
  }
  s0 += __shfl_down(s0, 32);
  s1 += __shfl_down(s1, 32);
  s2 += __shfl_down(s2, 32);
  s3 += __shfl_down(s3, 32);
  if (half == 0) {
    float4 o = ((float4*)out)[(long)n * 32 + c4];
    o.x += s0; o.y += s1; o.z += s2; o.w += s3;
    if (do_relu) {
      o.x = fmaxf(o.x, 0.f); o.y = fmaxf(o.y, 0.f);
      o.z = fmaxf(o.z, 0.f); o.w = fmaxf(o.w, 0.f);
    }
    ((float4*)out)[(long)n * 32 + c4] = o;
  }
}

// ---------------------------------------------------------------------------
// Fallback (tiny ws): fp32 init + GEMM + atomic scatter + relu
// ---------------------------------------------------------------------------
__global__ __launch_bounds__(256) void init_out_f32_kernel(
    const float* __restrict__ feat, const float* __restrict__ loop_w,
    const float* __restrict__ bias, float* __restrict__ out) {
  __shared__ float4 A4[64][32];
  int t = threadIdx.x;
  long base = (long)blockIdx.x * 64;
#pragma unroll
  for (int j = 0; j < 8; ++j) {
    int idx = t + j * 256;
    int e = idx >> 5, k4 = idx & 31;
    long n = base + e;
    float4 v = make_float4(0.f, 0.f, 0.f, 0.f);
    if (n < N_NODES) v = ((const float4*)feat)[n * 32 + k4];
    A4[e][k4] = v;
  }
  __syncthreads();
  int og = t & 31, eg = t >> 5;
  float acc[8][4];
#pragma unroll
  for (int j = 0; j < 8; ++j)
#pragma unroll
    for (int d = 0; d < 4; ++d) acc[j][d] = 0.f;
  const float4* W4 = (const float4*)loop_w;
  for (int k4 = 0; k4 < 32; ++k4) {
    float4 a[8];
#pragma unroll
    for (int j = 0; j < 8; ++j) a[j] = A4[eg * 8 + j][k4];
#pragma unroll
    for (int d = 0; d < 4; ++d) {
      float4 w = W4[(k4 * 4 + d) * 32 + og];
#pragma unroll
      for (int j = 0; j < 8; ++j) {
        float av = ((const float*)&a[j])[d];
        acc[j][0] += av * w.x;
        acc[j][1] += av * w.y;
        acc[j][2] += av * w.z;
        acc[j][3] += av * w.w;
      }
    }
  }
  float4 b = ((const float4*)bias)[og];
#pragma unroll
  for (int j = 0; j < 8; ++j) {
    long n = base + eg * 8 + j;
    if (n < N_NODES) {
      float4 v = make_float4(acc[j][0] + b.x, acc[j][1] + b.y,
                             acc[j][2] + b.z, acc[j][3] + b.w);
      ((float4*)out)[n * 32 + og] = v;
    }
  }
}

__global__ __launch_bounds__(256) void edge_msg_atomic_kernel(
    const float* __restrict__ feat, const float* __restrict__ W,
    const float* __restrict__ norm, const int* __restrict__ src,
    const int* __restrict__ dst, float* __restrict__ out) {
  __shared__ float4 A4[64][32];
  __shared__ int s_src[64];
  __shared__ int s_dst[64];
  __shared__ float s_norm[64];
  int t = threadIdx.x;
  long base = (long)blockIdx.x * 64;
  int rel = blockIdx.x >> 8;
  const float4* Wr4 = (const float4*)(W + (long)rel * IN_FEAT * OUT_FEAT);
  if (t < 64) {
    s_src[t] = src[base + t];
    s_dst[t] = dst[base + t];
    s_norm[t] = norm[base + t];
  }
  __syncthreads();
#pragma unroll
  for (int j = 0; j < 8; ++j) {
    int idx = t + j * 256;
    int e = idx >> 5, k4 = idx & 31;
    A4[e][k4] = ((const float4*)feat)[(long)s_src[e] * 32 + k4];
  }
  __syncthreads();
  int og = t & 31, eg = t >> 5;
  float acc[8][4];
#pragma unroll
  for (int j = 0; j < 8; ++j)
#pragma unroll
    for (int d = 0; d < 4; ++d) acc[j][d] = 0.f;
  for (int k4 = 0; k4 < 32; ++k4) {
    float4 a[8];
#pragma unroll
    for (int j = 0; j < 8; ++j) a[j] = A4[eg * 8 + j][k4];
#pragma unroll
    for (int d = 0; d < 4; ++d) {
      float4 w = Wr4[(k4 * 4 + d) * 32 + og];
#pragma unroll
      for (int j = 0; j < 8; ++j) {
        float av = ((const float*)&a[j])[d];
        acc[j][0] += av * w.x;
        acc[j][1] += av * w.y;
        acc[j][2] += av * w.z;
        acc[j][3] += av * w.w;
      }
    }
  }
#pragma unroll
  for (int j = 0; j < 8; ++j) {
    int e = eg * 8 + j;
    float nm = s_norm[e];
    float* orow = out + (long)s_dst[e] * OUT_FEAT + og * 4;
#pragma unroll
    for (int d = 0; d < 4; ++d) atomicAdd(orow + d, acc[j][d] * nm);
  }
}

__global__ __launch_bounds__(256) void relu_kernel(float* __restrict__ out) {
  int idx = blockIdx.x * 256 + threadIdx.x;
  float4 v = ((const float4*)out)[idx];
  v.x = fmaxf(v.x, 0.f);
  v.y = fmaxf(v.y, 0.f);
  v.z = fmaxf(v.z, 0.f);
  v.w = fmaxf(v.w, 0.f);
  ((float4*)out)[idx] = v;
}

extern "C" void kernel_launch(void* const* d_in, const int* in_sizes, int n_in,
                              void* d_out, int out_size, void* d_ws, size_t ws_size,
                              hipStream_t stream) {
  const float* feat   = (const float*)d_in[0];
  const float* weight = (const float*)d_in[1];
  const float* w_comp = (const float*)d_in[2];
  const float* h_bias = (const float*)d_in[3];
  const float* loop_w = (const float*)d_in[4];
  const float* norm   = (const float*)d_in[5];
  const int*   src    = (const int*)d_in[6];
  const int*   dst    = (const int*)d_in[7];
  float* out = (float*)d_out;

  const size_t SZ_WP  = (size_t)NUM_RELS * IN_FEAT * OUT_FEAT * 2;  // 2 MB
  const size_t SZ_LP  = (size_t)IN_FEAT * OUT_FEAT * 2;             // 32 KB
  const size_t SZ_POS = (size_t)E_TOTAL * 4;                        // 4 MB

  // CH=16 keeps msg chunk (67MB) + feat + out inside the 256MB L3.
  int CH = 0;
  {
    const int cands[3] = {16, 8, 4};
    for (int i = 0; i < 3 && CH == 0; ++i) {
      int ch = cands[i], nc = NUM_RELS / ch;
      size_t need = SZ_WP + SZ_LP + SZ_POS + 2 * (size_t)nc * N_PAD * 4 +
                    2 * (size_t)nc * NBLK * 4 +
                    (size_t)ch * EDGES_PER_REL * OUT_FEAT * 2;
      if (ws_size >= need) CH = ch;
    }
  }

  if (CH > 0) {
    const int NC = NUM_RELS / CH;
    const int chunk_edges = CH * EDGES_PER_REL;
    int cshift = 14;
    for (int x = CH; x > 1; x >>= 1) ++cshift;

    char* p = (char*)d_ws;
    __bf16* Wp = (__bf16*)p;                  p += SZ_WP;
    __bf16* Lp = (__bf16*)p;                  p += SZ_LP;
    int* pos  = (int*)p;                      p += SZ_POS;
    int* cnt8 = (int*)p;                      p += (size_t)NC * N_PAD * 4;
    int* row8 = (int*)p;                      p += (size_t)NC * N_PAD * 4;
    int* bsum = (int*)p;                      p += (size_t)NC * NBLK * 4;
    int* boff = (int*)p;                      p += (size_t)NC * NBLK * 4;
    unsigned short* msg = (unsigned short*)p;

    hipLaunchKernelGGL(pack_loop_w_kernel, dim3(16384 / 256), dim3(256), 0,
                       stream, loop_w, Lp);
    hipLaunchKernelGGL(init_out_mfma, dim3((N_NODES + 63) / 64), dim3(256), 0,
                       stream, feat, Lp, h_bias, out);
    hipLaunchKernelGGL(compose_w_bf16_kernel, dim3(NUM_RELS * 16384 / 256),
                       dim3(256), 0, stream, weight, w_comp, Wp);
    hipLaunchKernelGGL(zero_kernel, dim3(NC * NBLK), dim3(256), 0, stream, cnt8);
    hipLaunchKernelGGL(hist8_kernel, dim3(E_TOTAL / 256), dim3(256), 0, stream,
                       dst, cnt8, cshift);
    hipLaunchKernelGGL(scan1_kernel, dim3(NC * NBLK), dim3(256), 0, stream,
                       cnt8, row8, bsum);
    hipLaunchKernelGGL(scan2_kernel, dim3(NC), dim3(512), 0, stream, bsum, boff);
    hipLaunchKernelGGL(scan3_kernel, dim3(NC * NBLK), dim3(256), 0, stream,
                       row8, boff, cnt8);
    hipLaunchKernelGGL(scatter_pos_kernel, dim3(E_TOTAL / 256), dim3(256), 0,
                       stream, dst, cnt8, pos, cshift);

    for (int c = 0; c < NC; ++c) {
      hipLaunchKernelGGL(edge_gemm_mfma, dim3(chunk_edges / 128), dim3(256), 0,
                         stream, feat, Wp, norm, src, pos, msg,
                         c * chunk_edges);
      hipLaunchKernelGGL(gather_csr_kernel, dim3((N_NODES + 3) / 4), dim3(256),
                         0, stream, msg, row8 + (size_t)c * N_PAD, out,
                         (c == NC - 1) ? 1 : 0);
    }
  } else {
    float* W = (float*)d_ws;
    hipLaunchKernelGGL(init_out_f32_kernel, dim3((N_NODES + 63) / 64),
                       dim3(256), 0, stream, feat, loop_w, h_bias, out);
    hipLaunchKernelGGL(compose_w_f32_kernel, dim3(NUM_RELS * 16384 / 256),
                       dim3(256), 0, stream, weight, w_comp, W);
    hipLaunchKernelGGL(edge_msg_atomic_kernel, dim3(E_TOTAL / 64), dim3(256), 0,
                       stream, feat, W, norm, src, dst, out);
    hipLaunchKernelGGL(relu_kernel, dim3((N_NODES * OUT_FEAT / 4) / 256),
                       dim3(256), 0, stream, out);
  }
}

// Round 7
// 460.119 us; speedup vs baseline: 1.1664x; 1.1664x over previous
//
#include <hip/hip_runtime.h>

#define N_NODES 100000
#define N_PAD 100352          // 392 * 256
#define NBLK 392
#define IN_FEAT 128
#define OUT_FEAT 128
#define NUM_RELS 64
#define EDGES_PER_REL 16384
#define NUM_BASES 16
#define E_TOTAL (NUM_RELS * EDGES_PER_REL)

typedef __bf16 bf16x8 __attribute__((ext_vector_type(8)));
typedef float floatx4 __attribute__((ext_vector_type(4)));

// ---------------------------------------------------------------------------
// W composition -> bf16 k-packed layout Wp[r][kp][n][j], k = kp*8+j
// ---------------------------------------------------------------------------
__global__ __launch_bounds__(256) void compose_w_bf16_kernel(
    const float* __restrict__ weight, const float* __restrict__ w_comp,
    __bf16* __restrict__ Wp) {
  int idx = blockIdx.x * 256 + threadIdx.x;
  int r = idx >> 14;
  int off = idx & 16383;
  int j = off & 7, n = (off >> 3) & 127, kp = off >> 10;
  int k = kp * 8 + j;
  const float* wc = w_comp + r * NUM_BASES;
  float acc = 0.f;
#pragma unroll
  for (int b = 0; b < NUM_BASES; ++b)
    acc += wc[b] * weight[b * 16384 + k * 128 + n];
  Wp[idx] = (__bf16)acc;
}

// loop_weight -> bf16 k-packed layout Lp[kp][n][j]
__global__ __launch_bounds__(256) void pack_loop_w_kernel(
    const float* __restrict__ loop_w, __bf16* __restrict__ Lp) {
  int idx = blockIdx.x * 256 + threadIdx.x;    // 16384
  int j = idx & 7, n = (idx >> 3) & 127, kp = idx >> 10;
  Lp[idx] = (__bf16)loop_w[(kp * 8 + j) * 128 + n];
}

__global__ __launch_bounds__(256) void compose_w_f32_kernel(
    const float* __restrict__ weight, const float* __restrict__ w_comp,
    float* __restrict__ W) {
  int idx = blockIdx.x * 256 + threadIdx.x;
  int r = idx >> 14;
  int io = idx & 16383;
  const float* wc = w_comp + r * NUM_BASES;
  float acc = 0.f;
#pragma unroll
  for (int b = 0; b < NUM_BASES; ++b)
    acc += wc[b] * weight[b * 16384 + io];
  W[idx] = acc;
}

// ---------------------------------------------------------------------------
// out[n] = h_bias + feat[n] @ loop_weight   (MFMA bf16, 64 nodes / block)
// ---------------------------------------------------------------------------
__global__ __launch_bounds__(256) void init_out_mfma(
    const float* __restrict__ feat, const __bf16* __restrict__ Lp,
    const float* __restrict__ bias, float* __restrict__ out) {
  __shared__ __bf16 A_lds[64 * 136];
  int t = threadIdx.x;
  long base = (long)blockIdx.x * 64;
#pragma unroll
  for (int j = 0; j < 8; ++j) {
    int idx = t + j * 256;
    int e = idx >> 5, k4 = idx & 31;
    long n = base + e;
    float4 v = make_float4(0.f, 0.f, 0.f, 0.f);
    if (n < N_NODES) v = ((const float4*)feat)[n * 32 + k4];
    __bf16 tb[4] = {(__bf16)v.x, (__bf16)v.y, (__bf16)v.z, (__bf16)v.w};
    *(ushort4*)&A_lds[e * 136 + k4 * 4] = *(ushort4*)tb;
  }
  __syncthreads();

  int wave = t >> 6, lane = t & 63;
  int m16 = lane & 15, quad = lane >> 4;
  floatx4 acc[8];
#pragma unroll
  for (int nt = 0; nt < 8; ++nt) acc[nt] = (floatx4){0.f, 0.f, 0.f, 0.f};

  const __bf16* a_base = &A_lds[(wave * 16 + m16) * 136 + quad * 8];
#pragma unroll
  for (int ks = 0; ks < 4; ++ks) {
    bf16x8 a = *(const bf16x8*)(a_base + ks * 32);
    int kp = ks * 4 + quad;
#pragma unroll
    for (int nt = 0; nt < 8; ++nt) {
      bf16x8 b = *(const bf16x8*)(Lp + (kp * 128 + nt * 16 + m16) * 8);
      acc[nt] = __builtin_amdgcn_mfma_f32_16x16x32_bf16(a, b, acc[nt], 0, 0, 0);
    }
  }

  float bv[8];
#pragma unroll
  for (int nt = 0; nt < 8; ++nt) bv[nt] = bias[nt * 16 + m16];
#pragma unroll
  for (int r = 0; r < 4; ++r) {
    long n = base + wave * 16 + quad * 4 + r;
    if (n < N_NODES) {
#pragma unroll
      for (int nt = 0; nt < 8; ++nt)
        out[n * 128 + nt * 16 + m16] = acc[nt][r] + bv[nt];
    }
  }
}

// ---------------------------------------------------------------------------
// Per-chunk CSR build
// ---------------------------------------------------------------------------
__global__ __launch_bounds__(256) void zero_kernel(int* __restrict__ p) {
  p[blockIdx.x * 256 + threadIdx.x] = 0;
}

__global__ __launch_bounds__(256) void hist8_kernel(
    const int* __restrict__ dst, int* __restrict__ cnt8, int cshift) {
  int e = blockIdx.x * 256 + threadIdx.x;
  int c = e >> cshift;
  atomicAdd(&cnt8[c * N_PAD + dst[e]], 1);
}

__global__ __launch_bounds__(256) void scan1_kernel(
    const int* __restrict__ cnt, int* __restrict__ row,
    int* __restrict__ bsum) {
  __shared__ int s[256];
  int t = threadIdx.x;
  int idx = blockIdx.x * 256 + t;
  int v = cnt[idx];
  s[t] = v;
  __syncthreads();
  for (int o = 1; o < 256; o <<= 1) {
    int x = (t >= o) ? s[t - o] : 0;
    __syncthreads();
    s[t] += x;
    __syncthreads();
  }
  row[idx] = s[t] - v;
  if (t == 255) bsum[blockIdx.x] = s[t];
}

__global__ __launch_bounds__(512) void scan2_kernel(
    const int* __restrict__ bsum, int* __restrict__ boff) {
  __shared__ int s[512];
  int t = threadIdx.x;
  int v = (t < NBLK) ? bsum[blockIdx.x * NBLK + t] : 0;
  s[t] = v;
  __syncthreads();
  for (int o = 1; o < 512; o <<= 1) {
    int x = (t >= o) ? s[t - o] : 0;
    __syncthreads();
    s[t] += x;
    __syncthreads();
  }
  if (t < NBLK) boff[blockIdx.x * NBLK + t] = s[t] - v;
}

__global__ __launch_bounds__(256) void scan3_kernel(
    int* __restrict__ row, const int* __restrict__ boff,
    int* __restrict__ fill) {
  int idx = blockIdx.x * 256 + threadIdx.x;
  int v = row[idx] + boff[blockIdx.x];
  row[idx] = v;
  fill[idx] = v;
}

__global__ __launch_bounds__(256) void scatter_pos_kernel(
    const int* __restrict__ dst, int* __restrict__ fill8,
    int* __restrict__ pos, int cshift) {
  int e = blockIdx.x * 256 + threadIdx.x;
  int c = e >> cshift;
  pos[e] = atomicAdd(&fill8[c * N_PAD + dst[e]], 1);
}

// ---------------------------------------------------------------------------
// Phase A (MFMA): msg[pos[e]] = bf16((feat[src[e]] @ W[rel]) * norm[e])
// 64 edges/block, 4 waves, M=16/wave. LDS ~18KB -> 8 blocks/CU for latency
// hiding (M=32 variant measured SLOWER: 24% occupancy, 2.87 vs 3.35 TB/s).
// Epilogue bounces D through reused A_lds -> 256B-contiguous row stores.
// ---------------------------------------------------------------------------
__global__ __launch_bounds__(256) void edge_gemm_mfma(
    const float* __restrict__ feat, const __bf16* __restrict__ Wp,
    const float* __restrict__ norm, const int* __restrict__ src,
    const int* __restrict__ pos, unsigned short* __restrict__ msg, int e_lo) {
  __shared__ __bf16 A_lds[64 * 136];
  __shared__ int s_src[64];
  __shared__ int s_pos[64];
  __shared__ float s_norm[64];
  int t = threadIdx.x;
  long base = (long)e_lo + (long)blockIdx.x * 64;
  int rel = (int)(base >> 14);
  const __bf16* Wr = Wp + (long)rel * (IN_FEAT * OUT_FEAT);

  if (t < 64) {
    s_src[t] = src[base + t];
    s_pos[t] = pos[base + t];
    s_norm[t] = norm[base + t];
  }
  __syncthreads();
#pragma unroll
  for (int j = 0; j < 8; ++j) {
    int idx = t + j * 256;
    int e = idx >> 5, k4 = idx & 31;
    float4 v = ((const float4*)feat)[(long)s_src[e] * 32 + k4];
    __bf16 tb[4] = {(__bf16)v.x, (__bf16)v.y, (__bf16)v.z, (__bf16)v.w};
    *(ushort4*)&A_lds[e * 136 + k4 * 4] = *(ushort4*)tb;
  }
  __syncthreads();

  int wave = t >> 6, lane = t & 63;
  int m16 = lane & 15, quad = lane >> 4;
  floatx4 acc[8];
#pragma unroll
  for (int nt = 0; nt < 8; ++nt) acc[nt] = (floatx4){0.f, 0.f, 0.f, 0.f};

  const __bf16* a_base = &A_lds[(wave * 16 + m16) * 136 + quad * 8];
#pragma unroll
  for (int ks = 0; ks < 4; ++ks) {
    bf16x8 a = *(const bf16x8*)(a_base + ks * 32);
    int kp = ks * 4 + quad;
#pragma unroll
    for (int nt = 0; nt < 8; ++nt) {
      bf16x8 b = *(const bf16x8*)(Wr + (kp * 128 + nt * 16 + m16) * 8);
      acc[nt] = __builtin_amdgcn_mfma_f32_16x16x32_bf16(a, b, acc[nt], 0, 0, 0);
    }
  }

  // D (col=lane&15, row=quad*4+r) -> norm-scaled bf16 into reused A_lds tile
  __syncthreads();
#pragma unroll
  for (int r = 0; r < 4; ++r) {
    int erow = wave * 16 + quad * 4 + r;
    float nm = s_norm[erow];
#pragma unroll
    for (int nt = 0; nt < 8; ++nt)
      A_lds[erow * 136 + nt * 16 + m16] = (__bf16)(acc[nt][r] * nm);
  }
  __syncthreads();
  // re-read 16B/lane; each msg row written as one 256B contiguous burst
#pragma unroll
  for (int it = 0; it < 4; ++it) {
    int idx = it * 256 + t;
    int row = idx >> 4, seg = idx & 15;
    uint4 v = *(const uint4*)&A_lds[row * 136 + seg * 8];
    *(uint4*)(msg + (long)s_pos[row] * 128 + seg * 8) = v;
  }
}

// ---------------------------------------------------------------------------
// Phase B: CSR gather, 2 msg rows / iter (uint2/lane = 512B per wave-iter)
// msg reads are sequential across the chunk (CSR ordered by node).
// ---------------------------------------------------------------------------
__global__ __launch_bounds__(256) void gather_csr_kernel(
    const unsigned short* __restrict__ msg, const int* __restrict__ rowc,
    float* __restrict__ out, int do_relu) {
  int wave = threadIdx.x >> 6, lane = threadIdx.x & 63;
  int n = blockIdx.x * 4 + wave;
  if (n >= N_NODES) return;
  int beg = rowc[n], end = rowc[n + 1];
  if (!do_relu && beg == end) return;
  int half = lane >> 5;
  int c4 = lane & 31;
  float s0 = 0.f, s1 = 0.f, s2 = 0.f, s3 = 0.f;
  for (int j = beg + half; j < end; j += 2) {
    uint2 m = *(const uint2*)(msg + (long)j * 128 + c4 * 4);
    s0 += __uint_as_float(m.x << 16);
    s1 += __uint_as_float(m.x & 0xFFFF0000u);
    s2 += __uint_as_float(m.y << 16);
    s3 += __uint_as_float(m.y & 0xFFFF0000u);
  }
  s0 += __shfl_down(s0, 32);
  s1 += __shfl_down(s1, 32);
  s2 += __shfl_down(s2, 32);
  s3 += __shfl_down(s3, 32);
  if (half == 0) {
    float4 o = ((float4*)out)[(long)n * 32 + c4];
    o.x += s0; o.y += s1; o.z += s2; o.w += s3;
    if (do_relu) {
      o.x = fmaxf(o.x, 0.f); o.y = fmaxf(o.y, 0.f);
      o.z = fmaxf(o.z, 0.f); o.w = fmaxf(o.w, 0.f);
    }
    ((float4*)out)[(long)n * 32 + c4] = o;
  }
}

// ---------------------------------------------------------------------------
// Fallback (tiny ws): fp32 init + GEMM + atomic scatter + relu
// ---------------------------------------------------------------------------
__global__ __launch_bounds__(256) void init_out_f32_kernel(
    const float* __restrict__ feat, const float* __restrict__ loop_w,
    const float* __restrict__ bias, float* __restrict__ out) {
  __shared__ float4 A4[64][32];
  int t = threadIdx.x;
  long base = (long)blockIdx.x * 64;
#pragma unroll
  for (int j = 0; j < 8; ++j) {
    int idx = t + j * 256;
    int e = idx >> 5, k4 = idx & 31;
    long n = base + e;
    float4 v = make_float4(0.f, 0.f, 0.f, 0.f);
    if (n < N_NODES) v = ((const float4*)feat)[n * 32 + k4];
    A4[e][k4] = v;
  }
  __syncthreads();
  int og = t & 31, eg = t >> 5;
  float acc[8][4];
#pragma unroll
  for (int j = 0; j < 8; ++j)
#pragma unroll
    for (int d = 0; d < 4; ++d) acc[j][d] = 0.f;
  const float4* W4 = (const float4*)loop_w;
  for (int k4 = 0; k4 < 32; ++k4) {
    float4 a[8];
#pragma unroll
    for (int j = 0; j < 8; ++j) a[j] = A4[eg * 8 + j][k4];
#pragma unroll
    for (int d = 0; d < 4; ++d) {
      float4 w = W4[(k4 * 4 + d) * 32 + og];
#pragma unroll
      for (int j = 0; j < 8; ++j) {
        float av = ((const float*)&a[j])[d];
        acc[j][0] += av * w.x;
        acc[j][1] += av * w.y;
        acc[j][2] += av * w.z;
        acc[j][3] += av * w.w;
      }
    }
  }
  float4 b = ((const float4*)bias)[og];
#pragma unroll
  for (int j = 0; j < 8; ++j) {
    long n = base + eg * 8 + j;
    if (n < N_NODES) {
      float4 v = make_float4(acc[j][0] + b.x, acc[j][1] + b.y,
                             acc[j][2] + b.z, acc[j][3] + b.w);
      ((float4*)out)[n * 32 + og] = v;
    }
  }
}

__global__ __launch_bounds__(256) void edge_msg_atomic_kernel(
    const float* __restrict__ feat, const float* __restrict__ W,
    const float* __restrict__ norm, const int* __restrict__ src,
    const int* __restrict__ dst, float* __restrict__ out) {
  __shared__ float4 A4[64][32];
  __shared__ int s_src[64];
  __shared__ int s_dst[64];
  __shared__ float s_norm[64];
  int t = threadIdx.x;
  long base = (long)blockIdx.x * 64;
  int rel = blockIdx.x >> 8;
  const float4* Wr4 = (const float4*)(W + (long)rel * IN_FEAT * OUT_FEAT);
  if (t < 64) {
    s_src[t] = src[base + t];
    s_dst[t] = dst[base + t];
    s_norm[t] = norm[base + t];
  }
  __syncthreads();
#pragma unroll
  for (int j = 0; j < 8; ++j) {
    int idx = t + j * 256;
    int e = idx >> 5, k4 = idx & 31;
    A4[e][k4] = ((const float4*)feat)[(long)s_src[e] * 32 + k4];
  }
  __syncthreads();
  int og = t & 31, eg = t >> 5;
  float acc[8][4];
#pragma unroll
  for (int j = 0; j < 8; ++j)
#pragma unroll
    for (int d = 0; d < 4; ++d) acc[j][d] = 0.f;
  for (int k4 = 0; k4 < 32; ++k4) {
    float4 a[8];
#pragma unroll
    for (int j = 0; j < 8; ++j) a[j] = A4[eg * 8 + j][k4];
#pragma unroll
    for (int d = 0; d < 4; ++d) {
      float4 w = Wr4[(k4 * 4 + d) * 32 + og];
#pragma unroll
      for (int j = 0; j < 8; ++j) {
        float av = ((const float*)&a[j])[d];
        acc[j][0] += av * w.x;
        acc[j][1] += av * w.y;
        acc[j][2] += av * w.z;
        acc[j][3] += av * w.w;
      }
    }
  }
#pragma unroll
  for (int j = 0; j < 8; ++j) {
    int e = eg * 8 + j;
    float nm = s_norm[e];
    float* orow = out + (long)s_dst[e] * OUT_FEAT + og * 4;
#pragma unroll
    for (int d = 0; d < 4; ++d) atomicAdd(orow + d, acc[j][d] * nm);
  }
}

__global__ __launch_bounds__(256) void relu_kernel(float* __restrict__ out) {
  int idx = blockIdx.x * 256 + threadIdx.x;
  float4 v = ((const float4*)out)[idx];
  v.x = fmaxf(v.x, 0.f);
  v.y = fmaxf(v.y, 0.f);
  v.z = fmaxf(v.z, 0.f);
  v.w = fmaxf(v.w, 0.f);
  ((float4*)out)[idx] = v;
}

extern "C" void kernel_launch(void* const* d_in, const int* in_sizes, int n_in,
                              void* d_out, int out_size, void* d_ws, size_t ws_size,
                              hipStream_t stream) {
  const float* feat   = (const float*)d_in[0];
  const float* weight = (const float*)d_in[1];
  const float* w_comp = (const float*)d_in[2];
  const float* h_bias = (const float*)d_in[3];
  const float* loop_w = (const float*)d_in[4];
  const float* norm   = (const float*)d_in[5];
  const int*   src    = (const int*)d_in[6];
  const int*   dst    = (const int*)d_in[7];
  float* out = (float*)d_out;

  const size_t SZ_WP  = (size_t)NUM_RELS * IN_FEAT * OUT_FEAT * 2;  // 2 MB
  const size_t SZ_LP  = (size_t)IN_FEAT * OUT_FEAT * 2;             // 32 KB
  const size_t SZ_POS = (size_t)E_TOTAL * 4;                        // 4 MB

  // CH=32: fewest out-RMW passes that fits ws (>=142MB proven in round 4).
  int CH = 0;
  {
    const int cands[4] = {32, 16, 8, 4};
    for (int i = 0; i < 4 && CH == 0; ++i) {
      int ch = cands[i], nc = NUM_RELS / ch;
      size_t need = SZ_WP + SZ_LP + SZ_POS + 2 * (size_t)nc * N_PAD * 4 +
                    2 * (size_t)nc * NBLK * 4 +
                    (size_t)ch * EDGES_PER_REL * OUT_FEAT * 2;
      if (ws_size >= need) CH = ch;
    }
  }

  if (CH > 0) {
    const int NC = NUM_RELS / CH;
    const int chunk_edges = CH * EDGES_PER_REL;
    int cshift = 14;
    for (int x = CH; x > 1; x >>= 1) ++cshift;

    char* p = (char*)d_ws;
    __bf16* Wp = (__bf16*)p;                  p += SZ_WP;
    __bf16* Lp = (__bf16*)p;                  p += SZ_LP;
    int* pos  = (int*)p;                      p += SZ_POS;
    int* cnt8 = (int*)p;                      p += (size_t)NC * N_PAD * 4;
    int* row8 = (int*)p;                      p += (size_t)NC * N_PAD * 4;
    int* bsum = (int*)p;                      p += (size_t)NC * NBLK * 4;
    int* boff = (int*)p;                      p += (size_t)NC * NBLK * 4;
    unsigned short* msg = (unsigned short*)p;

    hipLaunchKernelGGL(pack_loop_w_kernel, dim3(16384 / 256), dim3(256), 0,
                       stream, loop_w, Lp);
    hipLaunchKernelGGL(init_out_mfma, dim3((N_NODES + 63) / 64), dim3(256), 0,
                       stream, feat, Lp, h_bias, out);
    hipLaunchKernelGGL(compose_w_bf16_kernel, dim3(NUM_RELS * 16384 / 256),
                       dim3(256), 0, stream, weight, w_comp, Wp);
    hipLaunchKernelGGL(zero_kernel, dim3(NC * NBLK), dim3(256), 0, stream, cnt8);
    hipLaunchKernelGGL(hist8_kernel, dim3(E_TOTAL / 256), dim3(256), 0, stream,
                       dst, cnt8, cshift);
    hipLaunchKernelGGL(scan1_kernel, dim3(NC * NBLK), dim3(256), 0, stream,
                       cnt8, row8, bsum);
    hipLaunchKernelGGL(scan2_kernel, dim3(NC), dim3(512), 0, stream, bsum, boff);
    hipLaunchKernelGGL(scan3_kernel, dim3(NC * NBLK), dim3(256), 0, stream,
                       row8, boff, cnt8);
    hipLaunchKernelGGL(scatter_pos_kernel, dim3(E_TOTAL / 256), dim3(256), 0,
                       stream, dst, cnt8, pos, cshift);

    for (int c = 0; c < NC; ++c) {
      hipLaunchKernelGGL(edge_gemm_mfma, dim3(chunk_edges / 64), dim3(256), 0,
                         stream, feat, Wp, norm, src, pos, msg,
                         c * chunk_edges);
      hipLaunchKernelGGL(gather_csr_kernel, dim3((N_NODES + 3) / 4), dim3(256),
                         0, stream, msg, row8 + (size_t)c * N_PAD, out,
                         (c == NC - 1) ? 1 : 0);
    }
  } else {
    float* W = (float*)d_ws;
    hipLaunchKernelGGL(init_out_f32_kernel, dim3((N_NODES + 63) / 64),
                       dim3(256), 0, stream, feat, loop_w, h_bias, out);
    hipLaunchKernelGGL(compose_w_f32_kernel, dim3(NUM_RELS * 16384 / 256),
                       dim3(256), 0, stream, weight, w_comp, W);
    hipLaunchKernelGGL(edge_msg_atomic_kernel, dim3(E_TOTAL / 64), dim3(256), 0,
                       stream, feat, W, norm, src, dst, out);
    hipLaunchKernelGGL(relu_kernel, dim3((N_NODES * OUT_FEAT / 4) / 256),
                       dim3(256), 0, stream, out);
  }
}